// Round 1
// baseline (51.127 us; speedup 1.0000x reference)
//
#include <hip/hip_runtime.h>

// Problem constants (from reference)
#define B_    16
#define N_    25200
#define NC_   80
#define NM_   32
#define NDET_ 100
#define H_    160
#define W_    160
#define HW_   (H_ * W_)
#define XDIM_ (5 + NC_ + NM_)   // 117
#define COEF_OFF_ (5 + NC_)     // 85

// Output layout (flat f32):
// [0,16)          num_det (int->float)
// [16,6416)       det_boxes
// [6416,8016)     det_scores
// [8016,9616)     det_classes (int->float)
// [9616, ...)     masks (B*NDET*HW)
#define OFF_BOXES_   16
#define OFF_SCORES_  6416
#define OFF_CLASSES_ 8016
#define OFF_MASKS_   9616

__global__ __launch_bounds__(256) void head_kernel(
    const int* __restrict__ num_det,
    const float* __restrict__ det_boxes,
    const float* __restrict__ det_scores,
    const int* __restrict__ det_classes,
    float* __restrict__ out)
{
    int i = blockIdx.x * 256 + threadIdx.x;
    if (i < 16) {
        out[i] = (float)num_det[i];
    } else if (i < OFF_SCORES_) {
        out[i] = det_boxes[i - OFF_BOXES_];
    } else if (i < OFF_CLASSES_) {
        out[i] = det_scores[i - OFF_SCORES_];
    } else if (i < OFF_MASKS_) {
        out[i] = (float)det_classes[i - OFF_CLASSES_];
    }
}

__global__ __launch_bounds__(256) void mask_kernel(
    const float* __restrict__ x0,
    const float* __restrict__ proto,
    const float* __restrict__ det_boxes,
    const int* __restrict__ det_indices,
    float* __restrict__ out_masks)   // points at out + OFF_MASKS_
{
    __shared__ float s_coef[NDET_ * NM_];   // 12.5 KB
    __shared__ float s_box[NDET_ * 4];      // 1.6 KB

    const int b = blockIdx.y;
    const int tile = blockIdx.x;            // 100 tiles of 256 pixels
    const int tid = threadIdx.x;

    // Gather coefficient matrix for this batch into LDS.
    // s_coef[o*32+m] = x0[b, det_indices[b,o], 85+m]
    for (int i = tid; i < NDET_ * NM_; i += 256) {
        int o = i >> 5;
        int m = i & 31;
        int idx = det_indices[b * NDET_ + o];
        s_coef[i] = x0[((size_t)b * N_ + idx) * XDIM_ + COEF_OFF_ + m];
    }
    // Prescaled boxes
    for (int i = tid; i < NDET_ * 4; i += 256) {
        s_box[i] = det_boxes[b * NDET_ * 4 + i] * 0.25f;
    }
    __syncthreads();

    const int p = tile * 256 + tid;         // pixel index in [0, HW)
    const float rf = (float)(p % W_);       // column (r in reference)
    const float cf = (float)(p / W_);       // row    (c in reference)

    // Load this pixel's proto column (32 values) into registers, coalesced.
    const float* __restrict__ pp = proto + (size_t)b * NM_ * HW_ + p;
    float pr[NM_];
#pragma unroll
    for (int m = 0; m < NM_; ++m) pr[m] = pp[(size_t)m * HW_];

    float* __restrict__ outp = out_masks + (size_t)b * NDET_ * HW_ + p;

    for (int o = 0; o < NDET_; ++o) {
        const float x1 = s_box[o * 4 + 0];
        const float y1 = s_box[o * 4 + 1];
        const float x2 = s_box[o * 4 + 2];
        const float y2 = s_box[o * 4 + 3];
        float v = 0.0f;
        bool in = (rf >= x1) & (rf < x2) & (cf >= y1) & (cf < y2);
        if (in) {
            float acc = 0.0f;
#pragma unroll
            for (int m = 0; m < NM_; ++m) acc += s_coef[o * NM_ + m] * pr[m];
            v = 1.0f / (1.0f + __expf(-acc));
        }
        outp[(size_t)o * HW_] = v;
    }
}

extern "C" void kernel_launch(void* const* d_in, const int* in_sizes, int n_in,
                              void* d_out, int out_size, void* d_ws, size_t ws_size,
                              hipStream_t stream)
{
    const float* x0          = (const float*)d_in[0];
    const float* proto       = (const float*)d_in[1];
    const int*   num_det     = (const int*)  d_in[2];
    const float* det_boxes   = (const float*)d_in[3];
    const float* det_scores  = (const float*)d_in[4];
    const int*   det_classes = (const int*)  d_in[5];
    const int*   det_indices = (const int*)  d_in[6];
    float* out = (float*)d_out;

    head_kernel<<<(OFF_MASKS_ + 255) / 256, 256, 0, stream>>>(
        num_det, det_boxes, det_scores, det_classes, out);

    dim3 grid(HW_ / 256, B_);
    mask_kernel<<<grid, 256, 0, stream>>>(
        x0, proto, det_boxes, det_indices, out + OFF_MASKS_);
}